// Round 35
// baseline (1487.088 us; speedup 1.0000x reference)
//
#include <hip/hip_runtime.h>
#include <math.h>

#define TT 16384      // B*S tokens
#define DD 2048       // hidden dim
#define EE 64         // experts
#define KTOP 8
#define BM 64         // rows per block (grid 256)
#define BK 32         // k-chunk
#define NT (DD / BK)  // 64 k-tiles
#define SL 4096       // seq len
#define BB 4          // batch
#define NTHR 512      // 8 waves
#define XSTR2 36      // X tile row-major stride (32 + 4)
#define WSTR 65       // W tile stride (64 + 1): conflict-free read AND write
#define LSTR 68       // logits stride

// numpy SIMD float32 exp (P/Q rational — locked)
__device__ __forceinline__ float np_expf(float x) {
    const float LOG2E = 1.442695040888963407359924681001892137f;
    const float MAGIC = 0x1.800000p+23f;
    const float C1 = -6.93145752e-1f;
    const float C2 = -1.42860677e-6f;
    float q = __fmul_rn(x, LOG2E);
    q = __fadd_rn(q, MAGIC);
    q = __fsub_rn(q, MAGIC);
    x = __fmaf_rn(q, C1, x);
    x = __fmaf_rn(q, C2, x);
    float num = __fmaf_rn(5.082762527590693718096e-04f, x, 6.757896990527504603057e-03f);
    num = __fmaf_rn(num, x, 5.114512081637298353406e-02f);
    num = __fmaf_rn(num, x, 2.473615434895520810817e-01f);
    num = __fmaf_rn(num, x, 7.257664613233124478488e-01f);
    num = __fmaf_rn(num, x, 9.999999999980870924916e-01f);
    float den = __fmaf_rn(2.159509375685829852307e-02f, x, -2.742335390411667452936e-01f);
    den = __fmaf_rn(den, x, 1.0f);
    const float quot = __fdiv_rn(num, den);
    const int qi = (int)q;
    const float sc = __uint_as_float((unsigned int)(127 + qi) << 23);
    return __fmul_rn(quot, sc);
}

// GEMM arithmetic (LOCKED): chunks [320 x5, 224, 224], folds at kt+1 in
// {10,20,30,40,50,57,64}; 2 banks, QUADS bank=(k>>2)&1, TREE combine.
__device__ __forceinline__ bool is_fold(int kt1) {
    return kt1 == 10 || kt1 == 20 || kt1 == 30 || kt1 == 40 ||
           kt1 == 50 || kt1 == 57 || kt1 == 64;
}

__global__ __launch_bounds__(NTHR) void moe_gate_main(
    const float* __restrict__ X, const float* __restrict__ W,
    float* __restrict__ out, float* __restrict__ ws_cnt, float* __restrict__ ws_ssum)
{
    __shared__ float Xs[2][BM * XSTR2];    // row-major X tile
    __shared__ float Wsh[2][BK * WSTR];    // [kk][expert]
    __shared__ float Ls[BM * LSTR];
    __shared__ float mrow[BM], zrow[BM];
    __shared__ float cnt[EE];

    const int tid  = threadIdx.x;
    const int row0 = blockIdx.x * BM;
    const int wid  = tid >> 6;    // wave 0..7 -> rows wid*8 .. wid*8+7
    const int lane = tid & 63;    // expert index

    float tot[8], acc[2][8];
#pragma unroll
    for (int i = 0; i < 8; ++i) { tot[i] = 0.f; acc[0][i] = 0.f; acc[1][i] = 0.f; }

    if (tid < EE) cnt[tid] = 0.f;

    // staging pointers (4 X + 4 W scalar loads per thread per tile)
    const float* xptr[4]; int xdst[4];
    const float* wptr[4]; int wdst[4];
#pragma unroll
    for (int j = 0; j < 4; ++j) {
        const int el = j * NTHR + tid;
        const int r = el >> 5, kk = el & 31;
        xptr[j] = X + (size_t)(row0 + r) * DD + kk;
        xdst[j] = r * XSTR2 + kk;            // row-major
        wptr[j] = W + (size_t)r * DD + kk;
        wdst[j] = kk * WSTR + r;             // [kk][expert]
    }

    float xr[4], wr[4];
#pragma unroll
    for (int j = 0; j < 4; ++j) { xr[j] = *xptr[j]; xptr[j] += BK; }
#pragma unroll
    for (int j = 0; j < 4; ++j) { wr[j] = *wptr[j]; wptr[j] += BK; }
#pragma unroll
    for (int j = 0; j < 4; ++j) Xs[0][xdst[j]] = xr[j];
#pragma unroll
    for (int j = 0; j < 4; ++j) Wsh[0][wdst[j]] = wr[j];

    for (int kt = 0; kt < NT; ++kt) {
        __syncthreads();
        const int cur = kt & 1;
        if (kt + 1 < NT) {   // issue next-tile global loads early
#pragma unroll
            for (int j = 0; j < 4; ++j) { xr[j] = *xptr[j]; xptr[j] += BK; }
#pragma unroll
            for (int j = 0; j < 4; ++j) { wr[j] = *wptr[j]; wptr[j] += BK; }
        }
        // W column for this lane (expert): 32 conflict-free b32 reads
        float wreg[32];
#pragma unroll
        for (int kk = 0; kk < BK; ++kk) wreg[kk] = Wsh[cur][kk * WSTR + lane];
        // 8 rows x 32 kk; bank = (kk>>2)&1 = g&1; exact locked chain order
#pragma unroll
        for (int rr = 0; rr < 8; ++rr) {
            const int r = wid * 8 + rr;
#pragma unroll
            for (int g = 0; g < 8; ++g) {
                const int p = g & 1;
                const float4 xv = *(const float4*)&Xs[cur][r * XSTR2 + 4 * g];
                acc[p][rr] = __fmaf_rn(xv.x, wreg[4 * g],     acc[p][rr]);
                acc[p][rr] = __fmaf_rn(xv.y, wreg[4 * g + 1], acc[p][rr]);
                acc[p][rr] = __fmaf_rn(xv.z, wreg[4 * g + 2], acc[p][rr]);
                acc[p][rr] = __fmaf_rn(xv.w, wreg[4 * g + 3], acc[p][rr]);
            }
        }
        if (is_fold(kt + 1)) {
#pragma unroll
            for (int rr = 0; rr < 8; ++rr) {
                tot[rr] = __fadd_rn(tot[rr], __fadd_rn(acc[0][rr], acc[1][rr]));
                acc[0][rr] = 0.f; acc[1][rr] = 0.f;
            }
        }
        if (kt + 1 < NT) {
#pragma unroll
            for (int j = 0; j < 4; ++j) Xs[cur ^ 1][xdst[j]] = xr[j];
#pragma unroll
            for (int j = 0; j < 4; ++j) Wsh[cur ^ 1][wdst[j]] = wr[j];
        }
    }

    // logits -> LDS: lane e writes its 8 rows (conflict-free across lanes)
#pragma unroll
    for (int rr = 0; rr < 8; ++rr)
        Ls[(wid * 8 + rr) * LSTR + lane] = tot[rr];
    __syncthreads();

    // P1: row max (64 threads)
    if (tid < BM) {
        const int r = tid;
        float m = Ls[r * LSTR];
#pragma unroll
        for (int e = 1; e < EE; ++e) m = fmaxf(m, Ls[r * LSTR + e]);
        mrow[r] = m;
    }
    __syncthreads();

    // P2: u = np.exp(l - m) in parallel (512 threads x 8 pairs), in place
#pragma unroll
    for (int j = 0; j < 8; ++j) {
        const int q2 = j * NTHR + tid;
        const int r = q2 >> 6, e = q2 & 63;
        Ls[r * LSTR + e] = np_expf(__fsub_rn(Ls[r * LSTR + e], mrow[r]));
    }
    __syncthreads();

    // P3: z per row — numpy pairwise (8 accumulators, exact order)
    if (tid < BM) {
        const int r = tid;
        float rr8[8];
#pragma unroll
        for (int j = 0; j < 8; ++j) rr8[j] = Ls[r * LSTR + j];
#pragma unroll
        for (int c = 1; c < 8; ++c)
#pragma unroll
            for (int j = 0; j < 8; ++j)
                rr8[j] = __fadd_rn(rr8[j], Ls[r * LSTR + 8 * c + j]);
        zrow[r] = __fadd_rn(
            __fadd_rn(__fadd_rn(rr8[0], rr8[1]), __fadd_rn(rr8[2], rr8[3])),
            __fadd_rn(__fadd_rn(rr8[4], rr8[5]), __fadd_rn(rr8[6], rr8[7])));
    }
    __syncthreads();

    // P4: s = u / z in parallel, in place
#pragma unroll
    for (int j = 0; j < 8; ++j) {
        const int q2 = j * NTHR + tid;
        const int r = q2 >> 6, e = q2 & 63;
        Ls[r * LSTR + e] = __fdiv_rn(Ls[r * LSTR + e], zrow[r]);
    }
    __syncthreads();

    // P5: top-8 per row (64 threads) — value desc, index ASC on exact ties
    if (tid < BM) {
        const int r = tid;
        float s[EE];
#pragma unroll
        for (int q2 = 0; q2 < 16; ++q2) {
            const float4 v = *(const float4*)&Ls[r * LSTR + 4 * q2];
            s[4 * q2] = v.x; s[4 * q2 + 1] = v.y; s[4 * q2 + 2] = v.z; s[4 * q2 + 3] = v.w;
        }
        float pv = 3.4e38f; int pi = -1;
        float wk[KTOP]; int ti[KTOP]; float wsum = 0.f;
#pragma unroll
        for (int k = 0; k < KTOP; ++k) {
            float best = -3.4e38f; int bi = 0;
#pragma unroll
            for (int e = 0; e < EE; ++e) {
                const bool elig   = (s[e] < pv) || ((s[e] == pv) && (e > pi));
                const bool better = elig && (s[e] > best);
                best = better ? s[e] : best;
                bi   = better ? e    : bi;
            }
            wk[k] = best; ti[k] = bi; wsum = __fadd_rn(wsum, best);
            pv = best; pi = bi;
        }
        const float den = __fadd_rn(wsum, 1e-20f);

        const size_t t = (size_t)row0 + r;
        float4 o0, o1;
        o0.x = (float)ti[0]; o0.y = (float)ti[1]; o0.z = (float)ti[2]; o0.w = (float)ti[3];
        o1.x = (float)ti[4]; o1.y = (float)ti[5]; o1.z = (float)ti[6]; o1.w = (float)ti[7];
        *(float4*)&out[t * 8]     = o0;
        *(float4*)&out[t * 8 + 4] = o1;
        float* outw = out + (size_t)TT * KTOP;
        o0.x = __fdiv_rn(wk[0], den); o0.y = __fdiv_rn(wk[1], den);
        o0.z = __fdiv_rn(wk[2], den); o0.w = __fdiv_rn(wk[3], den);
        o1.x = __fdiv_rn(wk[4], den); o1.y = __fdiv_rn(wk[5], den);
        o1.z = __fdiv_rn(wk[6], den); o1.w = __fdiv_rn(wk[7], den);
        *(float4*)&outw[t * 8]     = o0;
        *(float4*)&outw[t * 8 + 4] = o1;

#pragma unroll
        for (int k = 0; k < KTOP; ++k) atomicAdd(&cnt[ti[k]], 1.f);
    }
    __syncthreads();

    // P6: per-expert column sums (scores still in Ls)
    if (tid < EE) {
        const int e = tid;
        float cs = 0.f;
#pragma unroll
        for (int r2 = 0; r2 < BM; ++r2) cs += Ls[r2 * LSTR + e];
        const int b = row0 / SL;
        atomicAdd(&ws_ssum[b * EE + e], cs);
        atomicAdd(&ws_cnt[b * EE + e], cnt[e]);
    }
}

__global__ void moe_gate_aux(const float* __restrict__ ws_cnt,
                             const float* __restrict__ ws_ssum,
                             float* __restrict__ out_aux)
{
    __shared__ float red[4];
    const int tid = threadIdx.x;  // 256 = B*E cells
    float v = ws_cnt[tid] * ws_ssum[tid];
#pragma unroll
    for (int m = 32; m; m >>= 1) v += __shfl_xor(v, m, 64);
    if ((tid & 63) == 0) red[tid >> 6] = v;
    __syncthreads();
    if (tid == 0) {
        const float tot = red[0] + red[1] + red[2] + red[3];
        // aux = ALPHA * (1/B) * sum_{b,e} (cnt/(S*K/E)) * (ssum/S)
        out_aux[0] = tot * (1e-3f / ((float)BB * 512.f * (float)SL));
    }
}

extern "C" void kernel_launch(void* const* d_in, const int* in_sizes, int n_in,
                              void* d_out, int out_size, void* d_ws, size_t ws_size,
                              hipStream_t stream)
{
    const float* X = (const float*)d_in[0];
    const float* W = (const float*)d_in[1];
    float* out  = (float*)d_out;
    float* cnt  = (float*)d_ws;
    float* ssum = cnt + BB * EE;
    hipMemsetAsync(d_ws, 0, 2 * BB * EE * sizeof(float), stream);
    moe_gate_main<<<TT / BM, NTHR, 0, stream>>>(X, W, out, cnt, ssum);
    moe_gate_aux<<<1, 256, 0, stream>>>(cnt, ssum, out + (size_t)2 * TT * KTOP);
}

// Round 36
// 325.462 us; speedup vs baseline: 4.5692x; 4.5692x over previous
//
#include <hip/hip_runtime.h>
#include <math.h>

#define TT 16384      // B*S tokens
#define DD 2048       // hidden dim
#define EE 64         // experts
#define KTOP 8
#define BM 32         // rows per block -> grid 512 = 2 blocks/CU
#define BK 32         // k-chunk
#define NT (DD / BK)  // 64 k-tiles
#define SL 4096       // seq len
#define BB 4          // batch
#define NTHR 512      // 8 waves/block; 16 waves/CU total
#define XSTR 36       // X tile stride [kk][r], 32+4
#define WSTR 68       // W tile stride [kk][e], 64+4 (16B-aligned rows)
#define LSTR 68       // logits stride

// numpy SIMD float32 exp (P/Q rational — locked)
__device__ __forceinline__ float np_expf(float x) {
    const float LOG2E = 1.442695040888963407359924681001892137f;
    const float MAGIC = 0x1.800000p+23f;
    const float C1 = -6.93145752e-1f;
    const float C2 = -1.42860677e-6f;
    float q = __fmul_rn(x, LOG2E);
    q = __fadd_rn(q, MAGIC);
    q = __fsub_rn(q, MAGIC);
    x = __fmaf_rn(q, C1, x);
    x = __fmaf_rn(q, C2, x);
    float num = __fmaf_rn(5.082762527590693718096e-04f, x, 6.757896990527504603057e-03f);
    num = __fmaf_rn(num, x, 5.114512081637298353406e-02f);
    num = __fmaf_rn(num, x, 2.473615434895520810817e-01f);
    num = __fmaf_rn(num, x, 7.257664613233124478488e-01f);
    num = __fmaf_rn(num, x, 9.999999999980870924916e-01f);
    float den = __fmaf_rn(2.159509375685829852307e-02f, x, -2.742335390411667452936e-01f);
    den = __fmaf_rn(den, x, 1.0f);
    const float quot = __fdiv_rn(num, den);
    const int qi = (int)q;
    const float sc = __uint_as_float((unsigned int)(127 + qi) << 23);
    return __fmul_rn(quot, sc);
}

// GEMM arithmetic (LOCKED): chunks [320 x5, 224, 224], folds at kt+1 in
// {10,20,30,40,50,57,64}; 2 banks, QUADS bank=(k>>2)&1, TREE combine,
// one f32 add into C per chunk. (global k = kt*32+kk; (k>>2)&1 == (kk>>2)&1)
__device__ __forceinline__ bool is_fold(int kt1) {
    return kt1 == 10 || kt1 == 20 || kt1 == 30 || kt1 == 40 ||
           kt1 == 50 || kt1 == 57 || kt1 == 64;
}

__global__ __launch_bounds__(NTHR) void moe_gate_main(
    const float* __restrict__ X, const float* __restrict__ W,
    float* __restrict__ out, float* __restrict__ ws_cnt, float* __restrict__ ws_ssum)
{
    __shared__ float Xs[2][BK * XSTR];     // 9.2 KB
    __shared__ float Wsh[2][BK * WSTR];    // 17.4 KB
    __shared__ float Ls[BM * LSTR];        // 8.7 KB
    __shared__ float mrow[BM], zrow[BM];
    __shared__ float cnt[EE];

    const int tid  = threadIdx.x;
    const int row0 = blockIdx.x * BM;
    const int tr   = tid >> 4;    // 0..31 -> row
    const int tc   = tid & 15;    // 0..15 -> cols 4tc..4tc+3

    float tot[4], acc[2][4];
#pragma unroll
    for (int j = 0; j < 4; ++j) { tot[j] = 0.f; acc[0][j] = 0.f; acc[1][j] = 0.f; }

    if (tid < EE) cnt[tid] = 0.f;

    // staging: X 1024 el (2/thread), W 2048 el (4/thread); coalesced global
    const float* xptr[2]; int xdst[2];
#pragma unroll
    for (int j = 0; j < 2; ++j) {
        const int el = j * NTHR + tid;
        const int r = el >> 5, kk = el & 31;
        xptr[j] = X + (size_t)(row0 + r) * DD + kk;
        xdst[j] = kk * XSTR + r;
    }
    const float* wptr[4]; int wdst[4];
#pragma unroll
    for (int j = 0; j < 4; ++j) {
        const int el = j * NTHR + tid;
        const int r = el >> 5, kk = el & 31;
        wptr[j] = W + (size_t)r * DD + kk;
        wdst[j] = kk * WSTR + r;
    }

    float xr[2], wr[4];
#pragma unroll
    for (int j = 0; j < 2; ++j) { xr[j] = *xptr[j]; xptr[j] += BK; }
#pragma unroll
    for (int j = 0; j < 4; ++j) { wr[j] = *wptr[j]; wptr[j] += BK; }
#pragma unroll
    for (int j = 0; j < 2; ++j) Xs[0][xdst[j]] = xr[j];
#pragma unroll
    for (int j = 0; j < 4; ++j) Wsh[0][wdst[j]] = wr[j];

    for (int kt = 0; kt < NT; ++kt) {
        __syncthreads();
        const int cur = kt & 1;
        if (kt + 1 < NT) {   // issue next-tile global loads early
#pragma unroll
            for (int j = 0; j < 2; ++j) { xr[j] = *xptr[j]; xptr[j] += BK; }
#pragma unroll
            for (int j = 0; j < 4; ++j) { wr[j] = *wptr[j]; wptr[j] += BK; }
        }
        // locked chain: ascending kk, bank=(kk>>2)&1, scalar X broadcast +
        // b128 W read, 4 outputs/thread
#pragma unroll
        for (int kk = 0; kk < BK; ++kk) {
            const int p = (kk >> 2) & 1;
            const float xv = Xs[cur][kk * XSTR + tr];
            const float4 b = *(const float4*)&Wsh[cur][kk * WSTR + 4 * tc];
            acc[p][0] = __fmaf_rn(xv, b.x, acc[p][0]);
            acc[p][1] = __fmaf_rn(xv, b.y, acc[p][1]);
            acc[p][2] = __fmaf_rn(xv, b.z, acc[p][2]);
            acc[p][3] = __fmaf_rn(xv, b.w, acc[p][3]);
        }
        if (is_fold(kt + 1)) {
#pragma unroll
            for (int j = 0; j < 4; ++j) {
                tot[j] = __fadd_rn(tot[j], __fadd_rn(acc[0][j], acc[1][j]));
                acc[0][j] = 0.f; acc[1][j] = 0.f;
            }
        }
        if (kt + 1 < NT) {
#pragma unroll
            for (int j = 0; j < 2; ++j) Xs[cur ^ 1][xdst[j]] = xr[j];
#pragma unroll
            for (int j = 0; j < 4; ++j) Wsh[cur ^ 1][wdst[j]] = wr[j];
        }
    }

    // logits -> LDS
    {
        float4 v; v.x = tot[0]; v.y = tot[1]; v.z = tot[2]; v.w = tot[3];
        *(float4*)&Ls[tr * LSTR + 4 * tc] = v;
    }
    __syncthreads();

    // P1: row max (32 threads)
    if (tid < BM) {
        const int r = tid;
        float m = Ls[r * LSTR];
#pragma unroll
        for (int e = 1; e < EE; ++e) m = fmaxf(m, Ls[r * LSTR + e]);
        mrow[r] = m;
    }
    __syncthreads();

    // P2: u = np.exp(l - m), in place (512 thr x 4)
#pragma unroll
    for (int j = 0; j < 4; ++j) {
        const int q2 = j * NTHR + tid;
        const int r = q2 >> 6, e = q2 & 63;
        Ls[r * LSTR + e] = np_expf(__fsub_rn(Ls[r * LSTR + e], mrow[r]));
    }
    __syncthreads();

    // P3: z per row — numpy pairwise (8 accumulators, exact order)
    if (tid < BM) {
        const int r = tid;
        float rr8[8];
#pragma unroll
        for (int j = 0; j < 8; ++j) rr8[j] = Ls[r * LSTR + j];
#pragma unroll
        for (int c = 1; c < 8; ++c)
#pragma unroll
            for (int j = 0; j < 8; ++j)
                rr8[j] = __fadd_rn(rr8[j], Ls[r * LSTR + 8 * c + j]);
        zrow[r] = __fadd_rn(
            __fadd_rn(__fadd_rn(rr8[0], rr8[1]), __fadd_rn(rr8[2], rr8[3])),
            __fadd_rn(__fadd_rn(rr8[4], rr8[5]), __fadd_rn(rr8[6], rr8[7])));
    }
    __syncthreads();

    // P4: s = u / z, in place
#pragma unroll
    for (int j = 0; j < 4; ++j) {
        const int q2 = j * NTHR + tid;
        const int r = q2 >> 6, e = q2 & 63;
        Ls[r * LSTR + e] = __fdiv_rn(Ls[r * LSTR + e], zrow[r]);
    }
    __syncthreads();

    // P5: top-8 per row (32 threads) — value desc, index ASC on exact ties
    if (tid < BM) {
        const int r = tid;
        float s[EE];
#pragma unroll
        for (int q2 = 0; q2 < 16; ++q2) {
            const float4 v = *(const float4*)&Ls[r * LSTR + 4 * q2];
            s[4 * q2] = v.x; s[4 * q2 + 1] = v.y; s[4 * q2 + 2] = v.z; s[4 * q2 + 3] = v.w;
        }
        float pv = 3.4e38f; int pi = -1;
        float wk[KTOP]; int ti[KTOP]; float wsum = 0.f;
#pragma unroll
        for (int k = 0; k < KTOP; ++k) {
            float best = -3.4e38f; int bi = 0;
#pragma unroll
            for (int e = 0; e < EE; ++e) {
                const bool elig   = (s[e] < pv) || ((s[e] == pv) && (e > pi));
                const bool better = elig && (s[e] > best);
                best = better ? s[e] : best;
                bi   = better ? e    : bi;
            }
            wk[k] = best; ti[k] = bi; wsum = __fadd_rn(wsum, best);
            pv = best; pi = bi;
        }
        const float den = __fadd_rn(wsum, 1e-20f);

        const size_t t = (size_t)row0 + r;
        float4 o0, o1;
        o0.x = (float)ti[0]; o0.y = (float)ti[1]; o0.z = (float)ti[2]; o0.w = (float)ti[3];
        o1.x = (float)ti[4]; o1.y = (float)ti[5]; o1.z = (float)ti[6]; o1.w = (float)ti[7];
        *(float4*)&out[t * 8]     = o0;
        *(float4*)&out[t * 8 + 4] = o1;
        float* outw = out + (size_t)TT * KTOP;
        o0.x = __fdiv_rn(wk[0], den); o0.y = __fdiv_rn(wk[1], den);
        o0.z = __fdiv_rn(wk[2], den); o0.w = __fdiv_rn(wk[3], den);
        o1.x = __fdiv_rn(wk[4], den); o1.y = __fdiv_rn(wk[5], den);
        o1.z = __fdiv_rn(wk[6], den); o1.w = __fdiv_rn(wk[7], den);
        *(float4*)&outw[t * 8]     = o0;
        *(float4*)&outw[t * 8 + 4] = o1;

#pragma unroll
        for (int k = 0; k < KTOP; ++k) atomicAdd(&cnt[ti[k]], 1.f);
    }
    __syncthreads();

    // P6: per-expert column sums (scores still in Ls)
    if (tid < EE) {
        const int e = tid;
        float cs = 0.f;
#pragma unroll
        for (int r2 = 0; r2 < BM; ++r2) cs += Ls[r2 * LSTR + e];
        const int b = row0 / SL;
        atomicAdd(&ws_ssum[b * EE + e], cs);
        atomicAdd(&ws_cnt[b * EE + e], cnt[e]);
    }
}

__global__ void moe_gate_aux(const float* __restrict__ ws_cnt,
                             const float* __restrict__ ws_ssum,
                             float* __restrict__ out_aux)
{
    __shared__ float red[4];
    const int tid = threadIdx.x;  // 256 = B*E cells
    float v = ws_cnt[tid] * ws_ssum[tid];
#pragma unroll
    for (int m = 32; m; m >>= 1) v += __shfl_xor(v, m, 64);
    if ((tid & 63) == 0) red[tid >> 6] = v;
    __syncthreads();
    if (tid == 0) {
        const float tot = red[0] + red[1] + red[2] + red[3];
        // aux = ALPHA * (1/B) * sum_{b,e} (cnt/(S*K/E)) * (ssum/S)
        out_aux[0] = tot * (1e-3f / ((float)BB * 512.f * (float)SL));
    }
}

extern "C" void kernel_launch(void* const* d_in, const int* in_sizes, int n_in,
                              void* d_out, int out_size, void* d_ws, size_t ws_size,
                              hipStream_t stream)
{
    const float* X = (const float*)d_in[0];
    const float* W = (const float*)d_in[1];
    float* out  = (float*)d_out;
    float* cnt  = (float*)d_ws;
    float* ssum = cnt + BB * EE;
    hipMemsetAsync(d_ws, 0, 2 * BB * EE * sizeof(float), stream);
    moe_gate_main<<<TT / BM, NTHR, 0, stream>>>(X, W, out, cnt, ssum);
    moe_gate_aux<<<1, 256, 0, stream>>>(cnt, ssum, out + (size_t)2 * TT * KTOP);
}